// Round 1
// baseline (386.366 us; speedup 1.0000x reference)
//
#include <hip/hip_runtime.h>
#include <hip/hip_bf16.h>
#include <cstdint>
#include <cstddef>

#define WS7    7
#define NHEADS 8
#define HD     32
#define CDIM   256
#define HP     133
#define NWY    19
#define NWIN   361     // 19*19 windows
#define BATCH  8
#define HIMG   128
#define TOK    49      // WS*WS tokens per window
#define MTOK   64      // padded token count

typedef __attribute__((ext_vector_type(8))) short short8;
typedef __attribute__((ext_vector_type(4))) short short4v;
typedef __attribute__((ext_vector_type(4))) float f32x4;

// ---- LDS layout (byte offsets) ----
// Region A (40960 B): xbuf [64][264] bf16  ->  P scratch 8 x [64][40] bf16  ->  attnout [64][264] bf16
#define REGA_OFF   0
#define QBUF_OFF   40960          // [64][264] bf16 = 33792 B
#define KBUF_OFF   74752          // [64][264] bf16
#define VT_OFF     108544         // [256][72] bf16 = 36864 B  (V transposed: [head*32+d][token])
#define SMEM_BYTES 145408
#define XROW 264
#define VROW 72
#define PROW 40

__device__ __forceinline__ short f2bf(float f) {
  union { float f; uint32_t u; } v; v.f = f;
  uint32_t r = v.u + 0x7FFFu + ((v.u >> 16) & 1u);   // RNE
  return (short)(r >> 16);
}

__global__ void cvt_weights(const float* __restrict__ qkv_w, const float* __restrict__ proj_w,
                            short* __restrict__ qkvw_bf, short* __restrict__ projw_bf) {
  int stride = gridDim.x * blockDim.x;
  int i0 = blockIdx.x * blockDim.x + threadIdx.x;
  for (int i = i0; i < 768 * 256; i += stride) qkvw_bf[i] = f2bf(qkv_w[i]);
  for (int i = i0; i < 256 * 256; i += stride) projw_bf[i] = f2bf(proj_w[i]);
}

__global__ __launch_bounds__(512, 2) void swin_fused(
    const float* __restrict__ x, const short* __restrict__ qkvw,
    const float* __restrict__ qkv_b, const short* __restrict__ projw,
    const float* __restrict__ proj_b, const float* __restrict__ mask,
    float* __restrict__ out)
{
  extern __shared__ char smem[];
  const int tid  = threadIdx.x;
  const int wave = tid >> 6;
  const int lane = tid & 63;
  const int lg   = lane >> 4;   // 0..3
  const int ln   = lane & 15;   // 0..15
  const int blk  = blockIdx.x;
  const int b    = blk / NWIN;
  const int wdx  = blk - b * NWIN;
  const int wy   = wdx / NWY;
  const int wx   = wdx - wy * NWY;

  // ---- Phase 1: gather rolled/padded x window -> LDS bf16 [64][XROW]; rows>=49 zero ----
  for (int i = tid; i < MTOK * 64; i += 512) {
    int r  = i >> 6;       // token row
    int c4 = i & 63;       // float4 chunk within 256 channels
    short4v v = (short4v){0, 0, 0, 0};
    if (r < TOK) {
      int ty = r / WS7, tx = r - (r / WS7) * WS7;
      int sh = wy * WS7 + ty + 3; if (sh >= HP) sh -= HP;
      int sw = wx * WS7 + tx + 3; if (sw >= HP) sw -= HP;
      if (sh < HIMG && sw < HIMG) {
        const float4* p = reinterpret_cast<const float4*>(
            x + (((size_t)b * (HIMG * HIMG) + (size_t)sh * HIMG + sw) * CDIM + c4 * 4));
        float4 f = *p;
        v = (short4v){f2bf(f.x), f2bf(f.y), f2bf(f.z), f2bf(f.w)};
      }
    }
    *reinterpret_cast<short4v*>(smem + REGA_OFF + ((size_t)r * XROW + c4 * 4) * 2) = v;
  }
  __syncthreads();

  // ---- Phase 2: QKV GEMM (M=64, K=256). Wave h computes its head's 96 output cols ----
  const int h = wave;
  int colbase[6];
  colbase[0] = h * HD;        colbase[1] = h * HD + 16;
  colbase[2] = 256 + h * HD;  colbase[3] = 256 + h * HD + 16;
  colbase[4] = 512 + h * HD;  colbase[5] = 512 + h * HD + 16;

  f32x4 acc[4][6];
#pragma unroll
  for (int mt = 0; mt < 4; ++mt)
#pragma unroll
    for (int nt = 0; nt < 6; ++nt) acc[mt][nt] = (f32x4){0, 0, 0, 0};

#pragma unroll 2
  for (int ks = 0; ks < 8; ++ks) {
    int k0 = ks * 32 + lg * 8;
    short8 afr[4];
#pragma unroll
    for (int mt = 0; mt < 4; ++mt)
      afr[mt] = *reinterpret_cast<const short8*>(smem + REGA_OFF + ((mt * 16 + ln) * XROW + k0) * 2);
    short8 bfr[6];
#pragma unroll
    for (int nt = 0; nt < 6; ++nt)
      bfr[nt] = *reinterpret_cast<const short8*>(qkvw + (size_t)(colbase[nt] + ln) * CDIM + k0);
#pragma unroll
    for (int nt = 0; nt < 6; ++nt)
#pragma unroll
      for (int mt = 0; mt < 4; ++mt)
        acc[mt][nt] = __builtin_amdgcn_mfma_f32_16x16x32_bf16(afr[mt], bfr[nt], acc[mt][nt], 0, 0, 0);
  }

  // bias add, convert to bf16, store q,k row-major and v transposed
#pragma unroll
  for (int nt = 0; nt < 6; ++nt) {
    int col = colbase[nt] + ln;
    float bias = qkv_b[col];
    int localc = h * HD + (nt & 1) * 16 + ln;   // column within 256
    int which = nt >> 1;                        // 0=q 1=k 2=v
#pragma unroll
    for (int mt = 0; mt < 4; ++mt) {
#pragma unroll
      for (int r = 0; r < 4; ++r) {
        float val = acc[mt][nt][r] + bias;
        int row = mt * 16 + lg * 4 + r;
        short bv = f2bf(val);
        if (which == 0)
          *reinterpret_cast<short*>(smem + QBUF_OFF + (row * XROW + localc) * 2) = bv;
        else if (which == 1)
          *reinterpret_cast<short*>(smem + KBUF_OFF + (row * XROW + localc) * 2) = bv;
        else
          *reinterpret_cast<short*>(smem + VT_OFF + (localc * VROW + row) * 2) = bv;
      }
    }
  }
  __syncthreads();   // xbuf (region A) dead for ALL waves; P scratch may now reuse it

  // ---- Phase 3: attention for head h.  S = Q K^T (64x64, hd=32 => one K-step) ----
  f32x4 s[4][4];
#pragma unroll
  for (int mt = 0; mt < 4; ++mt)
#pragma unroll
    for (int nt = 0; nt < 4; ++nt) s[mt][nt] = (f32x4){0, 0, 0, 0};
  {
    int kq = h * HD + lg * 8;
    short8 qa[4], kb[4];
#pragma unroll
    for (int mt = 0; mt < 4; ++mt)
      qa[mt] = *reinterpret_cast<const short8*>(smem + QBUF_OFF + ((mt * 16 + ln) * XROW + kq) * 2);
#pragma unroll
    for (int nt = 0; nt < 4; ++nt)
      kb[nt] = *reinterpret_cast<const short8*>(smem + KBUF_OFF + ((nt * 16 + ln) * XROW + kq) * 2);
#pragma unroll
    for (int nt = 0; nt < 4; ++nt)
#pragma unroll
      for (int mt = 0; mt < 4; ++mt)
        s[mt][nt] = __builtin_amdgcn_mfma_f32_16x16x32_bf16(qa[mt], kb[nt], s[mt][nt], 0, 0, 0);
  }

  // scale + mask + softmax over keys (row q lives in 16 lanes sharing lg, 4 regs each)
  const float scale = 0.17677669529663687f;   // 32^-0.5
  const float* mw = mask + (size_t)wdx * (TOK * TOK);
#pragma unroll
  for (int mt = 0; mt < 4; ++mt) {
#pragma unroll
    for (int r = 0; r < 4; ++r) {
      int q = mt * 16 + lg * 4 + r;
      float sv[4];
#pragma unroll
      for (int nt = 0; nt < 4; ++nt) {
        int key = nt * 16 + ln;
        if (q < TOK && key < TOK)
          sv[nt] = s[mt][nt][r] * scale + mw[q * TOK + key];
        else
          sv[nt] = -1e30f;
      }
      float m = fmaxf(fmaxf(sv[0], sv[1]), fmaxf(sv[2], sv[3]));
      for (int d = 1; d < 16; d <<= 1) m = fmaxf(m, __shfl_xor(m, d));
      float sum = 0.f;
#pragma unroll
      for (int nt = 0; nt < 4; ++nt) { sv[nt] = __expf(sv[nt] - m); sum += sv[nt]; }
      for (int d = 1; d < 16; d <<= 1) sum += __shfl_xor(sum, d);
      float inv = 1.0f / sum;
#pragma unroll
      for (int nt = 0; nt < 4; ++nt) s[mt][nt][r] = sv[nt] * inv;
    }
  }

  // ---- PV: out = P V.  P goes through per-wave LDS scratch in two 32-key halves ----
  f32x4 o[4][2];
#pragma unroll
  for (int mt = 0; mt < 4; ++mt)
#pragma unroll
    for (int n2 = 0; n2 < 2; ++n2) o[mt][n2] = (f32x4){0, 0, 0, 0};
  char* pbase = smem + REGA_OFF + wave * (MTOK * PROW * 2);   // 5120 B per wave
#pragma unroll
  for (int half = 0; half < 2; ++half) {
#pragma unroll
    for (int nn = 0; nn < 2; ++nn) {
      int nt = half * 2 + nn;
#pragma unroll
      for (int mt = 0; mt < 4; ++mt)
#pragma unroll
        for (int r = 0; r < 4; ++r) {
          int q  = mt * 16 + lg * 4 + r;
          int kk = nn * 16 + ln;               // key within 32-key half
          *reinterpret_cast<short*>(pbase + (q * PROW + kk) * 2) = f2bf(s[mt][nt][r]);
        }
    }
    short8 pa[4], vb[2];
#pragma unroll
    for (int mt = 0; mt < 4; ++mt)
      pa[mt] = *reinterpret_cast<const short8*>(pbase + ((mt * 16 + ln) * PROW + lg * 8) * 2);
#pragma unroll
    for (int n2 = 0; n2 < 2; ++n2)
      vb[n2] = *reinterpret_cast<const short8*>(
          smem + VT_OFF + ((h * HD + n2 * 16 + ln) * VROW + half * 32 + lg * 8) * 2);
#pragma unroll
    for (int n2 = 0; n2 < 2; ++n2)
#pragma unroll
      for (int mt = 0; mt < 4; ++mt)
        o[mt][n2] = __builtin_amdgcn_mfma_f32_16x16x32_bf16(pa[mt], vb[n2], o[mt][n2], 0, 0, 0);
  }
  __syncthreads();   // all P-scratch use done; region A becomes attnout

  // write attnout [64][XROW] bf16 (head h owns cols h*32..h*32+31)
#pragma unroll
  for (int n2 = 0; n2 < 2; ++n2)
#pragma unroll
    for (int mt = 0; mt < 4; ++mt)
#pragma unroll
      for (int r = 0; r < 4; ++r) {
        int row = mt * 16 + lg * 4 + r;
        int col = h * HD + n2 * 16 + ln;
        *reinterpret_cast<short*>(smem + REGA_OFF + (row * XROW + col) * 2) = f2bf(o[mt][n2][r]);
      }
  __syncthreads();

  // ---- Phase 4: proj GEMM (M=64, N=256, K=256); wave h computes cols h*32..h*32+31 ----
  f32x4 pacc[4][2];
#pragma unroll
  for (int mt = 0; mt < 4; ++mt)
#pragma unroll
    for (int n2 = 0; n2 < 2; ++n2) pacc[mt][n2] = (f32x4){0, 0, 0, 0};
#pragma unroll 2
  for (int ks = 0; ks < 8; ++ks) {
    int k0 = ks * 32 + lg * 8;
    short8 afr[4];
#pragma unroll
    for (int mt = 0; mt < 4; ++mt)
      afr[mt] = *reinterpret_cast<const short8*>(smem + REGA_OFF + ((mt * 16 + ln) * XROW + k0) * 2);
    short8 bfr[2];
#pragma unroll
    for (int n2 = 0; n2 < 2; ++n2)
      bfr[n2] = *reinterpret_cast<const short8*>(projw + (size_t)(h * HD + n2 * 16 + ln) * CDIM + k0);
#pragma unroll
    for (int n2 = 0; n2 < 2; ++n2)
#pragma unroll
      for (int mt = 0; mt < 4; ++mt)
        pacc[mt][n2] = __builtin_amdgcn_mfma_f32_16x16x32_bf16(afr[mt], bfr[n2], pacc[mt][n2], 0, 0, 0);
  }

  // epilogue: bias + scatter (un-roll + crop)
#pragma unroll
  for (int n2 = 0; n2 < 2; ++n2) {
    int col = h * HD + n2 * 16 + ln;
    float bias = proj_b[col];
#pragma unroll
    for (int mt = 0; mt < 4; ++mt)
#pragma unroll
      for (int r = 0; r < 4; ++r) {
        int t = mt * 16 + lg * 4 + r;
        if (t < TOK) {
          int ty = t / WS7, tx = t - (t / WS7) * WS7;
          int sh = wy * WS7 + ty + 3; if (sh >= HP) sh -= HP;
          int sw = wx * WS7 + tx + 3; if (sw >= HP) sw -= HP;
          if (sh < HIMG && sw < HIMG)
            out[((size_t)b * (HIMG * HIMG) + (size_t)sh * HIMG + sw) * CDIM + col] =
                pacc[mt][n2][r] + bias;
        }
      }
  }
}

extern "C" void kernel_launch(void* const* d_in, const int* in_sizes, int n_in,
                              void* d_out, int out_size, void* d_ws, size_t ws_size,
                              hipStream_t stream) {
  const float* x      = (const float*)d_in[0];
  const float* qkv_w  = (const float*)d_in[1];
  const float* qkv_b  = (const float*)d_in[2];
  const float* proj_w = (const float*)d_in[3];
  const float* proj_b = (const float*)d_in[4];
  const float* mask   = (const float*)d_in[5];
  float* out          = (float*)d_out;

  short* qkvw_bf = (short*)d_ws;                               // 768*256*2 = 393216 B
  short* projw_bf = (short*)((char*)d_ws + 768 * 256 * 2);     // 256*256*2 = 131072 B

  hipLaunchKernelGGL(cvt_weights, dim3(256), dim3(256), 0, stream,
                     qkv_w, proj_w, qkvw_bf, projw_bf);

  hipFuncSetAttribute((const void*)swin_fused,
                      hipFuncAttributeMaxDynamicSharedMemorySize, SMEM_BYTES);
  hipLaunchKernelGGL(swin_fused, dim3(BATCH * NWIN), dim3(512), SMEM_BYTES, stream,
                     x, qkvw_bf, qkv_b, projw_bf, proj_b, mask, out);
}

// Round 2
// 316.863 us; speedup vs baseline: 1.2193x; 1.2193x over previous
//
#include <hip/hip_runtime.h>
#include <hip/hip_bf16.h>
#include <cstdint>
#include <cstddef>

#define WS7    7
#define NHEADS 8
#define HD     32
#define CDIM   256
#define HP     133
#define NWY    19
#define NWIN   361     // 19*19 windows
#define BATCH  8
#define HIMG   128
#define TOK    49      // WS*WS tokens per window
#define MTOK   64      // padded token count

typedef __attribute__((ext_vector_type(8))) short short8;
typedef __attribute__((ext_vector_type(4))) short short4v;
typedef __attribute__((ext_vector_type(4))) float f32x4;

// ---- LDS layout (byte offsets) ----
// region A: xbuf [64][XROW] bf16 (phase1-2)  -> attnout [64][XROW] bf16 (post-PV)
// region B: VT [256][VROW] bf16 (V transposed: [col][token])
#define XROW 264
#define VROW 72
#define VT_OFF     33792            // 64*264*2
#define SMEM_BYTES 70656            // + 256*72*2   => 2 blocks/CU

__device__ __forceinline__ short f2bf(float f) {
  union { float f; uint32_t u; } v; v.f = f;
  uint32_t r = v.u + 0x7FFFu + ((v.u >> 16) & 1u);   // RNE
  return (short)(r >> 16);
}

#if defined(__has_builtin)
#if __has_builtin(__builtin_amdgcn_mfma_f32_16x16x16bf16_1k)
#define HAVE_MFMA16 1
#endif
#endif

__device__ __forceinline__ f32x4 mfma16(short4v a, short4v b, f32x4 c) {
#ifdef HAVE_MFMA16
  return __builtin_amdgcn_mfma_f32_16x16x16bf16_1k(a, b, c, 0, 0, 0);
#else
  asm("v_mfma_f32_16x16x16_bf16 %0, %1, %2, %0" : "+v"(c) : "v"(a), "v"(b));
  return c;
#endif
}

__device__ __forceinline__ short4v cvt4(f32x4 v, f32x4 b, float sc) {
  return (short4v){ f2bf((v[0] + b[0]) * sc), f2bf((v[1] + b[1]) * sc),
                    f2bf((v[2] + b[2]) * sc), f2bf((v[3] + b[3]) * sc) };
}

__global__ void cvt_weights(const float* __restrict__ qkv_w, const float* __restrict__ proj_w,
                            short* __restrict__ qkvw_bf, short* __restrict__ projw_bf) {
  int stride = gridDim.x * blockDim.x;
  int i0 = blockIdx.x * blockDim.x + threadIdx.x;
  for (int i = i0; i < 768 * 256; i += stride) qkvw_bf[i] = f2bf(qkv_w[i]);
  for (int i = i0; i < 256 * 256; i += stride) projw_bf[i] = f2bf(proj_w[i]);
}

__global__ __launch_bounds__(512, 4) void swin_fused(
    const float* __restrict__ x, const short* __restrict__ qkvw,
    const float* __restrict__ qkv_b, const short* __restrict__ projw,
    const float* __restrict__ proj_b, const float* __restrict__ mask,
    float* __restrict__ out)
{
  extern __shared__ char smem[];
  const int tid  = threadIdx.x;
  const int wave = tid >> 6;
  const int lane = tid & 63;
  const int lg   = lane >> 4;   // 0..3
  const int ln   = lane & 15;   // 0..15
  const int blk  = blockIdx.x;
  const int b    = blk / NWIN;
  const int wdx  = blk - b * NWIN;
  const int wy   = wdx / NWY;
  const int wx   = wdx - wy * NWY;

  // ---- Phase 1: gather rolled/padded x window -> LDS bf16 [64][XROW]; rows>=49 zero ----
  for (int i = tid; i < MTOK * 64; i += 512) {
    int r  = i >> 6;       // token row
    int c4 = i & 63;       // float4 chunk within 256 channels
    short4v v = (short4v){0, 0, 0, 0};
    if (r < TOK) {
      int ty = r / WS7, tx = r - (r / WS7) * WS7;
      int sh = wy * WS7 + ty + 3; if (sh >= HP) sh -= HP;
      int sw = wx * WS7 + tx + 3; if (sw >= HP) sw -= HP;
      if (sh < HIMG && sw < HIMG) {
        const float4* p = reinterpret_cast<const float4*>(
            x + (((size_t)b * (HIMG * HIMG) + (size_t)sh * HIMG + sw) * CDIM + c4 * 4));
        float4 f = *p;
        v = (short4v){f2bf(f.x), f2bf(f.y), f2bf(f.z), f2bf(f.w)};
      }
    }
    *reinterpret_cast<short4v*>(smem + ((size_t)r * XROW + c4 * 4) * 2) = v;
  }
  __syncthreads();

  const int h = wave;
  const int qcol = h * HD;
  const int kcol = 256 + h * HD;
  const int vcol = 512 + h * HD;
  const float scale = 0.17677669529663687f;   // 32^-0.5

  // biases for this wave's lane-group slots (outcol = base + 16*ct + 4*lg + r)
  f32x4 bq[2], bk[2], bv[2];
#pragma unroll
  for (int ct = 0; ct < 2; ++ct) {
    bq[ct] = *reinterpret_cast<const f32x4*>(qkv_b + qcol + 16 * ct + 4 * lg);
    bk[ct] = *reinterpret_cast<const f32x4*>(qkv_b + kcol + 16 * ct + 4 * lg);
    bv[ct] = *reinterpret_cast<const f32x4*>(qkv_b + vcol + 16 * ct + 4 * lg);
  }

  // ---- Phase 2a: Q^T, K^T via swapped mfma: D[outcol, token] (lane=token, reg=outcol) ----
  f32x4 qk[4][4];   // [ct: q0,q1,k0,k1][token tile]
#pragma unroll
  for (int ct = 0; ct < 4; ++ct)
#pragma unroll
    for (int tt = 0; tt < 4; ++tt) qk[ct][tt] = (f32x4){0, 0, 0, 0};

#pragma unroll 2
  for (int ks = 0; ks < 8; ++ks) {
    int k0 = ks * 32 + lg * 8;
    short8 xb[4];
#pragma unroll
    for (int tt = 0; tt < 4; ++tt)
      xb[tt] = *reinterpret_cast<const short8*>(smem + ((16 * tt + ln) * XROW + k0) * 2);
    short8 wq[2], wk[2];
#pragma unroll
    for (int ct = 0; ct < 2; ++ct) {
      wq[ct] = *reinterpret_cast<const short8*>(qkvw + (size_t)(qcol + 16 * ct + ln) * CDIM + k0);
      wk[ct] = *reinterpret_cast<const short8*>(qkvw + (size_t)(kcol + 16 * ct + ln) * CDIM + k0);
    }
#pragma unroll
    for (int ct = 0; ct < 2; ++ct)
#pragma unroll
      for (int tt = 0; tt < 4; ++tt) {
        qk[ct][tt]     = __builtin_amdgcn_mfma_f32_16x16x32_bf16(wq[ct], xb[tt], qk[ct][tt], 0, 0, 0);
        qk[2 + ct][tt] = __builtin_amdgcn_mfma_f32_16x16x32_bf16(wk[ct], xb[tt], qk[2 + ct][tt], 0, 0, 0);
      }
  }

  // convert to bf16 fragments (Q gets the softmax scale folded in)
  short4v qf[2][4], kf[2][4];
#pragma unroll
  for (int ct = 0; ct < 2; ++ct)
#pragma unroll
    for (int tt = 0; tt < 4; ++tt) {
      qf[ct][tt] = cvt4(qk[ct][tt], bq[ct], scale);
      kf[ct][tt] = cvt4(qk[2 + ct][tt], bk[ct], 1.0f);
    }

  // ---- Phase 2b: V^T, written to LDS VT[d][token] ----
  {
    f32x4 va[2][4];
#pragma unroll
    for (int ct = 0; ct < 2; ++ct)
#pragma unroll
      for (int tt = 0; tt < 4; ++tt) va[ct][tt] = (f32x4){0, 0, 0, 0};
#pragma unroll 2
    for (int ks = 0; ks < 8; ++ks) {
      int k0 = ks * 32 + lg * 8;
      short8 xb[4];
#pragma unroll
      for (int tt = 0; tt < 4; ++tt)
        xb[tt] = *reinterpret_cast<const short8*>(smem + ((16 * tt + ln) * XROW + k0) * 2);
      short8 wv[2];
#pragma unroll
      for (int ct = 0; ct < 2; ++ct)
        wv[ct] = *reinterpret_cast<const short8*>(qkvw + (size_t)(vcol + 16 * ct + ln) * CDIM + k0);
#pragma unroll
      for (int ct = 0; ct < 2; ++ct)
#pragma unroll
        for (int tt = 0; tt < 4; ++tt)
          va[ct][tt] = __builtin_amdgcn_mfma_f32_16x16x32_bf16(wv[ct], xb[tt], va[ct][tt], 0, 0, 0);
    }
#pragma unroll
    for (int ct = 0; ct < 2; ++ct)
#pragma unroll
      for (int tt = 0; tt < 4; ++tt)
#pragma unroll
        for (int r = 0; r < 4; ++r) {
          int row = h * HD + 16 * ct + 4 * lg + r;       // d
          int col = 16 * tt + ln;                        // token
          *reinterpret_cast<short*>(smem + VT_OFF + (row * VROW + col) * 2) =
              f2bf(va[ct][tt][r] + bv[ct][r]);
        }
  }
  __syncthreads();   // xbuf dead for all waves; region A becomes attnout

  // ---- Phase 3: S^T = K Q^T via 16x16x16 (keys on regs/lane-groups, queries on lanes) ----
  f32x4 s[4][4];   // [key tile][query tile]
#pragma unroll
  for (int kt = 0; kt < 4; ++kt)
#pragma unroll
    for (int qt = 0; qt < 4; ++qt) s[kt][qt] = (f32x4){0, 0, 0, 0};
#pragma unroll
  for (int step = 0; step < 2; ++step)
#pragma unroll
    for (int kt = 0; kt < 4; ++kt)
#pragma unroll
      for (int qt = 0; qt < 4; ++qt)
        s[kt][qt] = mfma16(kf[step][kt], qf[step][qt], s[kt][qt]);

  // softmax per query (query = 16*qt + ln; keys at 16*kt + 4*lg + r)
  const float* mw = mask + (size_t)wdx * (TOK * TOK);
  short4v pf[4][4];   // [kt][qt] : PV A-fragments
#pragma unroll
  for (int qt = 0; qt < 4; ++qt) {
    int q = 16 * qt + ln;
    bool qa = (q < TOK);
#pragma unroll
    for (int kt = 0; kt < 4; ++kt)
#pragma unroll
      for (int r = 0; r < 4; ++r) {
        int key = 16 * kt + 4 * lg + r;
        float v = -1e30f;
        if (qa && key < TOK) v = s[kt][qt][r] + mw[q * TOK + key];
        s[kt][qt][r] = v;
      }
    float m = -1e30f;
#pragma unroll
    for (int kt = 0; kt < 4; ++kt)
#pragma unroll
      for (int r = 0; r < 4; ++r) m = fmaxf(m, s[kt][qt][r]);
    m = fmaxf(m, __shfl_xor(m, 16));
    m = fmaxf(m, __shfl_xor(m, 32));
    float sum = 0.f;
#pragma unroll
    for (int kt = 0; kt < 4; ++kt)
#pragma unroll
      for (int r = 0; r < 4; ++r) {
        float e = __expf(s[kt][qt][r] - m);
        s[kt][qt][r] = e; sum += e;
      }
    sum += __shfl_xor(sum, 16);
    sum += __shfl_xor(sum, 32);
    float inv = 1.0f / sum;
#pragma unroll
    for (int kt = 0; kt < 4; ++kt)
      pf[kt][qt] = (short4v){ f2bf(s[kt][qt][0] * inv), f2bf(s[kt][qt][1] * inv),
                              f2bf(s[kt][qt][2] * inv), f2bf(s[kt][qt][3] * inv) };
  }

  // ---- PV via 16x16x16: O[query, d] ----
  f32x4 o[4][2];
#pragma unroll
  for (int qt = 0; qt < 4; ++qt)
#pragma unroll
    for (int n2 = 0; n2 < 2; ++n2) o[qt][n2] = (f32x4){0, 0, 0, 0};
#pragma unroll
  for (int kt = 0; kt < 4; ++kt) {
    short4v vb0 = *reinterpret_cast<const short4v*>(
        smem + VT_OFF + ((h * HD + ln) * VROW + 16 * kt + 4 * lg) * 2);
    short4v vb1 = *reinterpret_cast<const short4v*>(
        smem + VT_OFF + ((h * HD + 16 + ln) * VROW + 16 * kt + 4 * lg) * 2);
#pragma unroll
    for (int qt = 0; qt < 4; ++qt) {
      o[qt][0] = mfma16(pf[kt][qt], vb0, o[qt][0]);
      o[qt][1] = mfma16(pf[kt][qt], vb1, o[qt][1]);
    }
  }

  // write attnout [64][XROW] bf16 over the xbuf region
#pragma unroll
  for (int qt = 0; qt < 4; ++qt)
#pragma unroll
    for (int n2 = 0; n2 < 2; ++n2)
#pragma unroll
      for (int r = 0; r < 4; ++r) {
        int row = 16 * qt + 4 * lg + r;
        int col = h * HD + 16 * n2 + ln;
        *reinterpret_cast<short*>(smem + (row * XROW + col) * 2) = f2bf(o[qt][n2][r]);
      }
  __syncthreads();

  // ---- Phase 4: proj GEMM (M=64, N=256, K=256); wave h computes cols h*32..h*32+31 ----
  f32x4 pacc[4][2];
#pragma unroll
  for (int mt = 0; mt < 4; ++mt)
#pragma unroll
    for (int n2 = 0; n2 < 2; ++n2) pacc[mt][n2] = (f32x4){0, 0, 0, 0};
#pragma unroll 2
  for (int ks = 0; ks < 8; ++ks) {
    int k0 = ks * 32 + lg * 8;
    short8 afr[4];
#pragma unroll
    for (int mt = 0; mt < 4; ++mt)
      afr[mt] = *reinterpret_cast<const short8*>(smem + ((16 * mt + ln) * XROW + k0) * 2);
    short8 bfr[2];
#pragma unroll
    for (int n2 = 0; n2 < 2; ++n2)
      bfr[n2] = *reinterpret_cast<const short8*>(projw + (size_t)(h * HD + 16 * n2 + ln) * CDIM + k0);
#pragma unroll
    for (int n2 = 0; n2 < 2; ++n2)
#pragma unroll
      for (int mt = 0; mt < 4; ++mt)
        pacc[mt][n2] = __builtin_amdgcn_mfma_f32_16x16x32_bf16(afr[mt], bfr[n2], pacc[mt][n2], 0, 0, 0);
  }

  // epilogue: bias + scatter (un-roll + crop)
#pragma unroll
  for (int n2 = 0; n2 < 2; ++n2) {
    int col = h * HD + 16 * n2 + ln;
    float bias = proj_b[col];
#pragma unroll
    for (int mt = 0; mt < 4; ++mt)
#pragma unroll
      for (int r = 0; r < 4; ++r) {
        int t = 16 * mt + 4 * lg + r;
        if (t < TOK) {
          int ty = t / WS7, tx = t - (t / WS7) * WS7;
          int sh = wy * WS7 + ty + 3; if (sh >= HP) sh -= HP;
          int sw = wx * WS7 + tx + 3; if (sw >= HP) sw -= HP;
          if (sh < HIMG && sw < HIMG)
            out[((size_t)b * (HIMG * HIMG) + (size_t)sh * HIMG + sw) * CDIM + col] =
                pacc[mt][n2][r] + bias;
        }
      }
  }
}

extern "C" void kernel_launch(void* const* d_in, const int* in_sizes, int n_in,
                              void* d_out, int out_size, void* d_ws, size_t ws_size,
                              hipStream_t stream) {
  const float* x      = (const float*)d_in[0];
  const float* qkv_w  = (const float*)d_in[1];
  const float* qkv_b  = (const float*)d_in[2];
  const float* proj_w = (const float*)d_in[3];
  const float* proj_b = (const float*)d_in[4];
  const float* mask   = (const float*)d_in[5];
  float* out          = (float*)d_out;

  short* qkvw_bf = (short*)d_ws;                               // 768*256*2 = 393216 B
  short* projw_bf = (short*)((char*)d_ws + 768 * 256 * 2);     // 256*256*2 = 131072 B

  hipLaunchKernelGGL(cvt_weights, dim3(256), dim3(256), 0, stream,
                     qkv_w, proj_w, qkvw_bf, projw_bf);

  hipFuncSetAttribute((const void*)swin_fused,
                      hipFuncAttributeMaxDynamicSharedMemorySize, SMEM_BYTES);
  hipLaunchKernelGGL(swin_fused, dim3(BATCH * NWIN), dim3(512), SMEM_BYTES, stream,
                     x, qkvw_bf, qkv_b, projw_bf, proj_b, mask, out);
}

// Round 3
// 273.694 us; speedup vs baseline: 1.4117x; 1.1577x over previous
//
#include <hip/hip_runtime.h>
#include <hip/hip_bf16.h>
#include <cstdint>
#include <cstddef>

#define WS7    7
#define NHEADS 8
#define HD     32
#define CDIM   256
#define HP     133
#define NWY    19
#define NWIN   361     // 19*19 windows
#define BATCH  8
#define HIMG   128
#define TOK    49      // WS*WS tokens per window
#define MTOK   64      // padded token count

typedef __attribute__((ext_vector_type(8))) short short8;
typedef __attribute__((ext_vector_type(4))) short short4v;
typedef __attribute__((ext_vector_type(4))) float f32x4;

// ---- LDS layout (byte offsets) ----
// region A: xbuf [64][XROW] bf16 (phase1-2)  -> attnout [64][XROW] bf16 (post-PV)
// region B: VT [256][VROW] bf16 (V transposed: [col][token])
#define XROW 264
#define VROW 72
#define VT_OFF     33792            // 64*264*2
#define SMEM_BYTES 70656            // + 256*72*2   => 2 blocks/CU

__device__ __forceinline__ short f2bf(float f) {
  union { float f; uint32_t u; } v; v.f = f;
  uint32_t r = v.u + 0x7FFFu + ((v.u >> 16) & 1u);   // RNE
  return (short)(r >> 16);
}

#if defined(__has_builtin)
#if __has_builtin(__builtin_amdgcn_mfma_f32_16x16x16bf16_1k)
#define HAVE_MFMA16 1
#endif
#endif

__device__ __forceinline__ f32x4 mfma16(short4v a, short4v b, f32x4 c) {
#ifdef HAVE_MFMA16
  return __builtin_amdgcn_mfma_f32_16x16x16bf16_1k(a, b, c, 0, 0, 0);
#else
  asm("v_mfma_f32_16x16x16_bf16 %0, %1, %2, %0" : "+v"(c) : "v"(a), "v"(b));
  return c;
#endif
}

__device__ __forceinline__ short4v cvt4(f32x4 v, f32x4 b, float sc) {
  return (short4v){ f2bf((v[0] + b[0]) * sc), f2bf((v[1] + b[1]) * sc),
                    f2bf((v[2] + b[2]) * sc), f2bf((v[3] + b[3]) * sc) };
}

// region code of a rolled-layout coordinate (row or col): 0: [0,126) 1: [126,130) 2: [130,133)
__device__ __forceinline__ int regcode(int c) { return (c < 126) ? 0 : ((c < 130) ? 1 : 2); }

__global__ void cvt_weights(const float* __restrict__ qkv_w, const float* __restrict__ proj_w,
                            short* __restrict__ qkvw_bf, short* __restrict__ projw_bf) {
  int stride = gridDim.x * blockDim.x;
  int i0 = blockIdx.x * blockDim.x + threadIdx.x;
  for (int i = i0; i < 768 * 256; i += stride) qkvw_bf[i] = f2bf(qkv_w[i]);
  for (int i = i0; i < 256 * 256; i += stride) projw_bf[i] = f2bf(proj_w[i]);
}

__global__ __launch_bounds__(512, 4) void swin_fused(
    const float* __restrict__ x, const short* __restrict__ qkvw,
    const float* __restrict__ qkv_b, const short* __restrict__ projw,
    const float* __restrict__ proj_b, float* __restrict__ out)
{
  extern __shared__ char smem[];
  const int tid  = threadIdx.x;
  const int wave = tid >> 6;
  const int lane = tid & 63;
  const int lg   = lane >> 4;   // 0..3
  const int ln   = lane & 15;   // 0..15
  const int blk  = blockIdx.x;
  const int b    = blk / NWIN;
  const int wdx  = blk - b * NWIN;
  const int wy   = wdx / NWY;
  const int wx   = wdx - wy * NWY;

  // ---- Phase 1: gather rolled/padded x window -> LDS bf16 [64][XROW]; rows>=49 zero ----
  for (int i = tid; i < MTOK * 64; i += 512) {
    int r  = i >> 6;       // token row
    int c4 = i & 63;       // float4 chunk within 256 channels
    short4v v = (short4v){0, 0, 0, 0};
    if (r < TOK) {
      int ty = r / WS7, tx = r - (r / WS7) * WS7;
      int sh = wy * WS7 + ty + 3; if (sh >= HP) sh -= HP;
      int sw = wx * WS7 + tx + 3; if (sw >= HP) sw -= HP;
      if (sh < HIMG && sw < HIMG) {
        const float4* p = reinterpret_cast<const float4*>(
            x + (((size_t)b * (HIMG * HIMG) + (size_t)sh * HIMG + sw) * CDIM + c4 * 4));
        float4 f = *p;
        v = (short4v){f2bf(f.x), f2bf(f.y), f2bf(f.z), f2bf(f.w)};
      }
    }
    *reinterpret_cast<short4v*>(smem + ((size_t)r * XROW + c4 * 4) * 2) = v;
  }
  __syncthreads();

  const int h = wave;
  const int qcol = h * HD;
  const int kcol = 256 + h * HD;
  const int vcol = 512 + h * HD;
  const float scale = 0.17677669529663687f;   // 32^-0.5

  f32x4 acc[2][4];
  short4v qf[2][4], kf[2][4];

  // ---- Pass Q: Q^T via swapped mfma: D[outcol, token] (lane=token, reg=outcol) ----
#pragma unroll
  for (int ct = 0; ct < 2; ++ct)
#pragma unroll
    for (int tt = 0; tt < 4; ++tt) acc[ct][tt] = (f32x4){0, 0, 0, 0};
#pragma unroll 2
  for (int ks = 0; ks < 8; ++ks) {
    int k0 = ks * 32 + lg * 8;
    short8 xb[4];
#pragma unroll
    for (int tt = 0; tt < 4; ++tt)
      xb[tt] = *reinterpret_cast<const short8*>(smem + ((16 * tt + ln) * XROW + k0) * 2);
    short8 w[2];
#pragma unroll
    for (int ct = 0; ct < 2; ++ct)
      w[ct] = *reinterpret_cast<const short8*>(qkvw + (size_t)(qcol + 16 * ct + ln) * CDIM + k0);
#pragma unroll
    for (int ct = 0; ct < 2; ++ct)
#pragma unroll
      for (int tt = 0; tt < 4; ++tt)
        acc[ct][tt] = __builtin_amdgcn_mfma_f32_16x16x32_bf16(w[ct], xb[tt], acc[ct][tt], 0, 0, 0);
  }
#pragma unroll
  for (int ct = 0; ct < 2; ++ct) {
    f32x4 bias = *reinterpret_cast<const f32x4*>(qkv_b + qcol + 16 * ct + 4 * lg);
#pragma unroll
    for (int tt = 0; tt < 4; ++tt) qf[ct][tt] = cvt4(acc[ct][tt], bias, scale);
  }

  // ---- Pass K ----
#pragma unroll
  for (int ct = 0; ct < 2; ++ct)
#pragma unroll
    for (int tt = 0; tt < 4; ++tt) acc[ct][tt] = (f32x4){0, 0, 0, 0};
#pragma unroll 2
  for (int ks = 0; ks < 8; ++ks) {
    int k0 = ks * 32 + lg * 8;
    short8 xb[4];
#pragma unroll
    for (int tt = 0; tt < 4; ++tt)
      xb[tt] = *reinterpret_cast<const short8*>(smem + ((16 * tt + ln) * XROW + k0) * 2);
    short8 w[2];
#pragma unroll
    for (int ct = 0; ct < 2; ++ct)
      w[ct] = *reinterpret_cast<const short8*>(qkvw + (size_t)(kcol + 16 * ct + ln) * CDIM + k0);
#pragma unroll
    for (int ct = 0; ct < 2; ++ct)
#pragma unroll
      for (int tt = 0; tt < 4; ++tt)
        acc[ct][tt] = __builtin_amdgcn_mfma_f32_16x16x32_bf16(w[ct], xb[tt], acc[ct][tt], 0, 0, 0);
  }
#pragma unroll
  for (int ct = 0; ct < 2; ++ct) {
    f32x4 bias = *reinterpret_cast<const f32x4*>(qkv_b + kcol + 16 * ct + 4 * lg);
#pragma unroll
    for (int tt = 0; tt < 4; ++tt) kf[ct][tt] = cvt4(acc[ct][tt], bias, 1.0f);
  }

  // ---- Pass V: V^T -> LDS VT[d][token] ----
#pragma unroll
  for (int ct = 0; ct < 2; ++ct)
#pragma unroll
    for (int tt = 0; tt < 4; ++tt) acc[ct][tt] = (f32x4){0, 0, 0, 0};
#pragma unroll 2
  for (int ks = 0; ks < 8; ++ks) {
    int k0 = ks * 32 + lg * 8;
    short8 xb[4];
#pragma unroll
    for (int tt = 0; tt < 4; ++tt)
      xb[tt] = *reinterpret_cast<const short8*>(smem + ((16 * tt + ln) * XROW + k0) * 2);
    short8 w[2];
#pragma unroll
    for (int ct = 0; ct < 2; ++ct)
      w[ct] = *reinterpret_cast<const short8*>(qkvw + (size_t)(vcol + 16 * ct + ln) * CDIM + k0);
#pragma unroll
    for (int ct = 0; ct < 2; ++ct)
#pragma unroll
      for (int tt = 0; tt < 4; ++tt)
        acc[ct][tt] = __builtin_amdgcn_mfma_f32_16x16x32_bf16(w[ct], xb[tt], acc[ct][tt], 0, 0, 0);
  }
#pragma unroll
  for (int ct = 0; ct < 2; ++ct) {
    f32x4 bias = *reinterpret_cast<const f32x4*>(qkv_b + vcol + 16 * ct + 4 * lg);
#pragma unroll
    for (int tt = 0; tt < 4; ++tt)
#pragma unroll
      for (int r = 0; r < 4; ++r) {
        int row = h * HD + 16 * ct + 4 * lg + r;       // d
        int col = 16 * tt + ln;                        // token
        *reinterpret_cast<short*>(smem + VT_OFF + (row * VROW + col) * 2) =
            f2bf(acc[ct][tt][r] + bias[r]);
      }
  }
  __syncthreads();   // xbuf dead for all waves; region A becomes attnout

  // ---- Phase 3: S^T = K Q^T via 16x16x16 (keys on regs/lane-groups, queries on lanes) ----
  f32x4 s[4][4];   // [key tile][query tile]
#pragma unroll
  for (int kt = 0; kt < 4; ++kt)
#pragma unroll
    for (int qt = 0; qt < 4; ++qt) s[kt][qt] = (f32x4){0, 0, 0, 0};
#pragma unroll
  for (int step = 0; step < 2; ++step)
#pragma unroll
    for (int kt = 0; kt < 4; ++kt)
#pragma unroll
      for (int qt = 0; qt < 4; ++qt)
        s[kt][qt] = mfma16(kf[step][kt], qf[step][qt], s[kt][qt]);

  // softmax per query (query = 16*qt + ln; keys at 16*kt + 4*lg + r)
  // Swin shift-mask computed analytically: -100 iff region codes differ.
  // Codes are all-zero except boundary windows (wy==18 || wx==18).
  const bool bnd = (wy == NWY - 1) || (wx == NWY - 1);
  short4v pf[4][4];   // [kt][qt] : PV A-fragments
#pragma unroll
  for (int qt = 0; qt < 4; ++qt) {
    int q = 16 * qt + ln;
    int qcode = 0;
    if (bnd) {
      int qy = (q * 37) >> 8, qx = q - 7 * qy;
      qcode = 3 * regcode(wy * WS7 + qy) + regcode(wx * WS7 + qx);
    }
#pragma unroll
    for (int kt = 0; kt < 4; ++kt)
#pragma unroll
      for (int r = 0; r < 4; ++r) {
        int key = 16 * kt + 4 * lg + r;
        float v = s[kt][qt][r];
        if (bnd) {
          int ky = (key * 37) >> 8, kx = key - 7 * ky;
          int kc = 3 * regcode(wy * WS7 + ky) + regcode(wx * WS7 + kx);
          if (kc != qcode) v -= 100.0f;
        }
        if (key >= TOK) v = -1e30f;
        s[kt][qt][r] = v;
      }
    float m = -1e30f;
#pragma unroll
    for (int kt = 0; kt < 4; ++kt)
#pragma unroll
      for (int r = 0; r < 4; ++r) m = fmaxf(m, s[kt][qt][r]);
    m = fmaxf(m, __shfl_xor(m, 16));
    m = fmaxf(m, __shfl_xor(m, 32));
    float sum = 0.f;
#pragma unroll
    for (int kt = 0; kt < 4; ++kt)
#pragma unroll
      for (int r = 0; r < 4; ++r) {
        float e = __expf(s[kt][qt][r] - m);
        s[kt][qt][r] = e; sum += e;
      }
    sum += __shfl_xor(sum, 16);
    sum += __shfl_xor(sum, 32);
    float inv = 1.0f / sum;
#pragma unroll
    for (int kt = 0; kt < 4; ++kt)
      pf[kt][qt] = (short4v){ f2bf(s[kt][qt][0] * inv), f2bf(s[kt][qt][1] * inv),
                              f2bf(s[kt][qt][2] * inv), f2bf(s[kt][qt][3] * inv) };
  }

  // ---- PV via 16x16x16: O[query, d] (lane=channel, reg=query) ----
  f32x4 o[4][2];
#pragma unroll
  for (int qt = 0; qt < 4; ++qt)
#pragma unroll
    for (int n2 = 0; n2 < 2; ++n2) o[qt][n2] = (f32x4){0, 0, 0, 0};
#pragma unroll
  for (int kt = 0; kt < 4; ++kt) {
    short4v vb0 = *reinterpret_cast<const short4v*>(
        smem + VT_OFF + ((h * HD + ln) * VROW + 16 * kt + 4 * lg) * 2);
    short4v vb1 = *reinterpret_cast<const short4v*>(
        smem + VT_OFF + ((h * HD + 16 + ln) * VROW + 16 * kt + 4 * lg) * 2);
#pragma unroll
    for (int qt = 0; qt < 4; ++qt) {
      o[qt][0] = mfma16(pf[kt][qt], vb0, o[qt][0]);
      o[qt][1] = mfma16(pf[kt][qt], vb1, o[qt][1]);
    }
  }

  // write attnout [64][XROW] bf16 over the xbuf region
#pragma unroll
  for (int qt = 0; qt < 4; ++qt)
#pragma unroll
    for (int n2 = 0; n2 < 2; ++n2)
#pragma unroll
      for (int r = 0; r < 4; ++r) {
        int row = 16 * qt + 4 * lg + r;
        int col = h * HD + 16 * n2 + ln;
        *reinterpret_cast<short*>(smem + (row * XROW + col) * 2) = f2bf(o[qt][n2][r]);
      }
  __syncthreads();

  // ---- Phase 4: proj GEMM (M=64, N=256, K=256); wave h computes cols h*32..h*32+31 ----
  f32x4 pacc[4][2];
#pragma unroll
  for (int mt = 0; mt < 4; ++mt)
#pragma unroll
    for (int n2 = 0; n2 < 2; ++n2) pacc[mt][n2] = (f32x4){0, 0, 0, 0};
#pragma unroll 2
  for (int ks = 0; ks < 8; ++ks) {
    int k0 = ks * 32 + lg * 8;
    short8 afr[4];
#pragma unroll
    for (int mt = 0; mt < 4; ++mt)
      afr[mt] = *reinterpret_cast<const short8*>(smem + ((16 * mt + ln) * XROW + k0) * 2);
    short8 bfr[2];
#pragma unroll
    for (int n2 = 0; n2 < 2; ++n2)
      bfr[n2] = *reinterpret_cast<const short8*>(projw + (size_t)(h * HD + 16 * n2 + ln) * CDIM + k0);
#pragma unroll
    for (int n2 = 0; n2 < 2; ++n2)
#pragma unroll
      for (int mt = 0; mt < 4; ++mt)
        pacc[mt][n2] = __builtin_amdgcn_mfma_f32_16x16x32_bf16(afr[mt], bfr[n2], pacc[mt][n2], 0, 0, 0);
  }

  // epilogue: bias + scatter (un-roll + crop); both 64B halves of a 128B line back-to-back
  float pb0 = proj_b[h * HD + ln];
  float pb1 = proj_b[h * HD + 16 + ln];
#pragma unroll
  for (int mt = 0; mt < 4; ++mt)
#pragma unroll
    for (int r = 0; r < 4; ++r) {
      int t = 16 * mt + 4 * lg + r;
      if (t < TOK) {
        int ty = t / WS7, tx = t - (t / WS7) * WS7;
        int sh = wy * WS7 + ty + 3; if (sh >= HP) sh -= HP;
        int sw = wx * WS7 + tx + 3; if (sw >= HP) sw -= HP;
        if (sh < HIMG && sw < HIMG) {
          float* po = out + ((size_t)b * (HIMG * HIMG) + (size_t)sh * HIMG + sw) * CDIM + h * HD + ln;
          po[0]  = pacc[mt][0][r] + pb0;
          po[16] = pacc[mt][1][r] + pb1;
        }
      }
    }
}

extern "C" void kernel_launch(void* const* d_in, const int* in_sizes, int n_in,
                              void* d_out, int out_size, void* d_ws, size_t ws_size,
                              hipStream_t stream) {
  const float* x      = (const float*)d_in[0];
  const float* qkv_w  = (const float*)d_in[1];
  const float* qkv_b  = (const float*)d_in[2];
  const float* proj_w = (const float*)d_in[3];
  const float* proj_b = (const float*)d_in[4];
  float* out          = (float*)d_out;

  short* qkvw_bf = (short*)d_ws;                               // 768*256*2 = 393216 B
  short* projw_bf = (short*)((char*)d_ws + 768 * 256 * 2);     // 256*256*2 = 131072 B

  hipLaunchKernelGGL(cvt_weights, dim3(256), dim3(256), 0, stream,
                     qkv_w, proj_w, qkvw_bf, projw_bf);

  hipFuncSetAttribute((const void*)swin_fused,
                      hipFuncAttributeMaxDynamicSharedMemorySize, SMEM_BYTES);
  hipLaunchKernelGGL(swin_fused, dim3(BATCH * NWIN), dim3(512), SMEM_BYTES, stream,
                     x, qkvw_bf, qkv_b, projw_bf, proj_b, out);
}

// Round 6
// 269.989 us; speedup vs baseline: 1.4310x; 1.0137x over previous
//
#include <hip/hip_runtime.h>
#include <hip/hip_bf16.h>
#include <cstdint>
#include <cstddef>

#define WS7    7
#define NHEADS 8
#define HD     32
#define CDIM   256
#define HP     133
#define NWY    19
#define NWIN   361     // 19*19 windows
#define BATCH  8
#define HIMG   128
#define TOK    49      // WS*WS tokens per window
#define MTOK   64      // padded token count
#define SHIFT3 3

typedef __attribute__((ext_vector_type(8))) short short8;
typedef __attribute__((ext_vector_type(4))) short short4v;
typedef __attribute__((ext_vector_type(4))) float f32x4;

// ---- LDS layout (byte offsets) ----
// region A: xbuf [64][264] bf16 (phase1-2)  -> attnout [64][264] bf16 (post-PV)
// region B: VT [256][VROW] bf16 (V transposed: [channel][token]), VROW=76
#define XROWB  528                         // row stride in BYTES (264 bf16)
#define VROW   76
#define VT_OFF 33792                       // 64*528
#define SMEM_BYTES (VT_OFF + 256*VROW*2)   // 72704 => 2 blocks/CU

#define QS      0.25505653712988137f       // 32^-0.5 * log2(e)
#define MASKL2 -144.26950408889634f        // -100 * log2(e)

__device__ __forceinline__ short f2bf(float f) {
  union { float f; uint32_t u; } v; v.f = f;
  uint32_t r = v.u + 0x7FFFu + ((v.u >> 16) & 1u);   // RNE
  return (short)(r >> 16);
}

__device__ __forceinline__ uint32_t pk2(float a, float b) {
  union { __hip_bfloat162 h; uint32_t u; } cv;
  cv.h = __float22bfloat162_rn(float2{a, b});
  return cv.u;
}

#if defined(__has_builtin)
#if __has_builtin(__builtin_amdgcn_exp2f)
#define EXP2F __builtin_amdgcn_exp2f
#else
#define EXP2F exp2f
#endif
#else
#define EXP2F exp2f
#endif

#if defined(__has_builtin)
#if __has_builtin(__builtin_amdgcn_mfma_f32_16x16x16bf16_1k)
#define HAVE_MFMA16 1
#endif
#endif

__device__ __forceinline__ f32x4 mfma16(short4v a, short4v b, f32x4 c) {
#ifdef HAVE_MFMA16
  return __builtin_amdgcn_mfma_f32_16x16x16bf16_1k(a, b, c, 0, 0, 0);
#else
  asm("v_mfma_f32_16x16x16_bf16 %0, %1, %2, %0" : "+v"(c) : "v"(a), "v"(b));
  return c;
#endif
}

// region code of a rolled-layout coordinate: 0: [0,126) 1: [126,130) 2: [130,...)
__device__ __forceinline__ int regcode(int c) { return (c < 126) ? 0 : ((c < 130) ? 1 : 2); }

__global__ void cvt_weights(const float* __restrict__ qkv_w, const float* __restrict__ proj_w,
                            short* __restrict__ qkvw_bf, short* __restrict__ projw_bf) {
  int stride = gridDim.x * blockDim.x;
  int i0 = blockIdx.x * blockDim.x + threadIdx.x;
  for (int i = i0; i < 768 * 256; i += stride) qkvw_bf[i] = f2bf(qkv_w[i]);
  for (int i = i0; i < 256 * 256; i += stride) projw_bf[i] = f2bf(proj_w[i]);
}

__global__ __launch_bounds__(512, 4) void swin_fused(
    const float* __restrict__ x, const short* __restrict__ qkvw,
    const float* __restrict__ qkv_b, const short* __restrict__ projw,
    const float* __restrict__ proj_b, float* __restrict__ out)
{
  extern __shared__ char smem[];
  const int tid  = threadIdx.x;
  const int wave = tid >> 6;
  const int lane = tid & 63;
  const int lg   = lane >> 4;   // 0..3
  const int ln   = lane & 15;   // 0..15
  const int blk  = blockIdx.x;
  const int b    = blk / NWIN;
  const int wdx  = blk - b * NWIN;
  const int wy   = wdx / NWY;
  const int wx   = wdx - wy * NWY;

  // ---- Phase 1: gather rolled/padded x window -> LDS bf16 [64][264]; rows>=49 zero ----
  {
    const int c4 = lane;   // float4 chunk 0..63
#pragma unroll
    for (int it = 0; it < 8; ++it) {
      int r = 8 * it + wave;
      uint2 v = make_uint2(0u, 0u);
      if (r < TOK) {
        int ty = r / WS7, tx = r - WS7 * (r / WS7);
        int sh = wy * WS7 + ty + SHIFT3; if (sh >= HP) sh -= HP;
        int sw = wx * WS7 + tx + SHIFT3; if (sw >= HP) sw -= HP;
        if (sh < HIMG && sw < HIMG) {
          const float4 f = *reinterpret_cast<const float4*>(
              x + (((size_t)b * (HIMG * HIMG) + sh * HIMG + sw) * CDIM + c4 * 4));
          v = make_uint2(pk2(f.x, f.y), pk2(f.z, f.w));
        }
      }
      *reinterpret_cast<uint2*>(smem + r * XROWB + c4 * 8) = v;
    }
  }
  __syncthreads();

  const int h = wave;
  const int qcol = h * HD;
  const int kcol = 256 + h * HD;
  const int vcol = 512 + h * HD;

  f32x4 acc[2][4];
  short4v qf[2][4], kf[2][4];

#define QKV_PASS(COLBASE)                                                          \
  _Pragma("unroll")                                                                \
  for (int ct = 0; ct < 2; ++ct)                                                   \
    _Pragma("unroll")                                                              \
    for (int tt = 0; tt < 4; ++tt) acc[ct][tt] = (f32x4){0, 0, 0, 0};              \
  _Pragma("unroll 2")                                                              \
  for (int ks = 0; ks < 8; ++ks) {                                                 \
    const int k0 = ks * 32 + lg * 8;                                               \
    short8 xb[4];                                                                  \
    _Pragma("unroll")                                                              \
    for (int tt = 0; tt < 4; ++tt)                                                 \
      xb[tt] = *reinterpret_cast<const short8*>(smem + (16 * tt + ln) * XROWB + k0 * 2); \
    short8 w[2];                                                                   \
    _Pragma("unroll")                                                              \
    for (int ct = 0; ct < 2; ++ct)                                                 \
      w[ct] = *reinterpret_cast<const short8*>(qkvw + (size_t)((COLBASE) + 16 * ct + ln) * CDIM + k0); \
    _Pragma("unroll")                                                              \
    for (int ct = 0; ct < 2; ++ct)                                                 \
      _Pragma("unroll")                                                            \
      for (int tt = 0; tt < 4; ++tt)                                               \
        acc[ct][tt] = __builtin_amdgcn_mfma_f32_16x16x32_bf16(w[ct], xb[tt], acc[ct][tt], 0, 0, 0); \
  }

  // ---- Pass Q: Q^T (lane=token, reg=channel); fold scale*log2e ----
  QKV_PASS(qcol)
#pragma unroll
  for (int ct = 0; ct < 2; ++ct) {
    f32x4 bias = *reinterpret_cast<const f32x4*>(qkv_b + qcol + 16 * ct + 4 * lg);
#pragma unroll
    for (int tt = 0; tt < 4; ++tt) {
      float e0 = fmaf(acc[ct][tt][0], QS, bias[0] * QS);
      float e1 = fmaf(acc[ct][tt][1], QS, bias[1] * QS);
      float e2 = fmaf(acc[ct][tt][2], QS, bias[2] * QS);
      float e3 = fmaf(acc[ct][tt][3], QS, bias[3] * QS);
      union { uint2 u; short4v s; } cv;
      cv.u = make_uint2(pk2(e0, e1), pk2(e2, e3));
      qf[ct][tt] = cv.s;
    }
  }

  // ---- Pass K ----
  QKV_PASS(kcol)
#pragma unroll
  for (int ct = 0; ct < 2; ++ct) {
    f32x4 bias = *reinterpret_cast<const f32x4*>(qkv_b + kcol + 16 * ct + 4 * lg);
#pragma unroll
    for (int tt = 0; tt < 4; ++tt) {
      union { uint2 u; short4v s; } cv;
      cv.u = make_uint2(pk2(acc[ct][tt][0] + bias[0], acc[ct][tt][1] + bias[1]),
                        pk2(acc[ct][tt][2] + bias[2], acc[ct][tt][3] + bias[3]));
      kf[ct][tt] = cv.s;
    }
  }

  // ---- Pass V: V^T -> LDS VT[channel][token], pair-writes along channel ----
  QKV_PASS(vcol)
#pragma unroll
  for (int ct = 0; ct < 2; ++ct) {
    f32x4 bias = *reinterpret_cast<const f32x4*>(qkv_b + vcol + 16 * ct + 4 * lg);
#pragma unroll
    for (int tt = 0; tt < 4; ++tt) {
      uint32_t p01 = pk2(acc[ct][tt][0] + bias[0], acc[ct][tt][1] + bias[1]);
      uint32_t p23 = pk2(acc[ct][tt][2] + bias[2], acc[ct][tt][3] + bias[3]);
      int row0 = h * HD + 16 * ct + 4 * lg;
      int col  = 16 * tt + ln;
      char* base = smem + VT_OFF + (row0 * VROW + col) * 2;
      *reinterpret_cast<short*>(base)            = (short)(p01 & 0xFFFF);
      *reinterpret_cast<short*>(base + VROW * 2) = (short)(p01 >> 16);
      *reinterpret_cast<short*>(base + VROW * 4) = (short)(p23 & 0xFFFF);
      *reinterpret_cast<short*>(base + VROW * 6) = (short)(p23 >> 16);
    }
  }
  __syncthreads();   // all waves done reading xbuf; region A becomes attnout

  // ---- Phase 3: S^T = K Q^T via 16x16x16 (R3-proven flow: full tile, max-subtract) ----
  f32x4 s[4][4];   // [key tile][query tile]
#pragma unroll
  for (int kt = 0; kt < 4; ++kt)
#pragma unroll
    for (int qt = 0; qt < 4; ++qt) s[kt][qt] = (f32x4){0, 0, 0, 0};
#pragma unroll
  for (int step = 0; step < 2; ++step)
#pragma unroll
    for (int kt = 0; kt < 4; ++kt)
#pragma unroll
      for (int qt = 0; qt < 4; ++qt)
        s[kt][qt] = mfma16(kf[step][kt], qf[step][qt], s[kt][qt]);

  const bool bnd = (wy == NWY - 1) || (wx == NWY - 1);
  short4v pf[4][4];   // [kt][qt] : PV A-fragments (normalized P)
#pragma unroll
  for (int qt = 0; qt < 4; ++qt) {
    int q = 16 * qt + ln;
    int qcode = 0;
    if (bnd) {
      int qy = q / WS7, qx = q - WS7 * (q / WS7);
      qcode = 3 * regcode(wy * WS7 + qy) + regcode(wx * WS7 + qx);
    }
#pragma unroll
    for (int kt = 0; kt < 4; ++kt)
#pragma unroll
      for (int r = 0; r < 4; ++r) {
        int key = 16 * kt + 4 * lg + r;
        float v = s[kt][qt][r];
        if (bnd) {
          int ky = key / WS7, kx = key - WS7 * (key / WS7);
          int kc = 3 * regcode(wy * WS7 + ky) + regcode(wx * WS7 + kx);
          v += (kc != qcode) ? MASKL2 : 0.f;
        }
        if (key >= TOK) v = -1e30f;
        s[kt][qt][r] = v;
      }
    float m = -1e30f;
#pragma unroll
    for (int kt = 0; kt < 4; ++kt)
#pragma unroll
      for (int r = 0; r < 4; ++r) m = fmaxf(m, s[kt][qt][r]);
    m = fmaxf(m, __shfl_xor(m, 16));
    m = fmaxf(m, __shfl_xor(m, 32));
    float sum = 0.f;
#pragma unroll
    for (int kt = 0; kt < 4; ++kt)
#pragma unroll
      for (int r = 0; r < 4; ++r) {
        float e = EXP2F(s[kt][qt][r] - m);
        s[kt][qt][r] = e; sum += e;
      }
    sum += __shfl_xor(sum, 16);
    sum += __shfl_xor(sum, 32);
    float inv = 1.0f / sum;
#pragma unroll
    for (int kt = 0; kt < 4; ++kt) {
      union { uint2 u; short4v sv; } cv;
      cv.u = make_uint2(pk2(s[kt][qt][0] * inv, s[kt][qt][1] * inv),
                        pk2(s[kt][qt][2] * inv, s[kt][qt][3] * inv));
      pf[kt][qt] = cv.sv;
    }
  }

  // ---- PV via 16x16x16: lane ln owns channel pair (2ln, 2ln+1) ----
  f32x4 o[4][2];
#pragma unroll
  for (int qt = 0; qt < 4; ++qt)
#pragma unroll
    for (int n2 = 0; n2 < 2; ++n2) o[qt][n2] = (f32x4){0, 0, 0, 0};
#pragma unroll
  for (int kt = 0; kt < 4; ++kt) {
    int tok = 16 * kt + 4 * lg;
    short4v vb0 = *reinterpret_cast<const short4v*>(
        smem + VT_OFF + ((h * HD + 2 * ln) * VROW + tok) * 2);
    short4v vb1 = *reinterpret_cast<const short4v*>(
        smem + VT_OFF + ((h * HD + 2 * ln + 1) * VROW + tok) * 2);
#pragma unroll
    for (int qt = 0; qt < 4; ++qt) {
      o[qt][0] = mfma16(pf[kt][qt], vb0, o[qt][0]);
      o[qt][1] = mfma16(pf[kt][qt], vb1, o[qt][1]);
    }
  }

  // write attnout as packed b32: row = query, cols (h*32+2ln, h*32+2ln+1)
#pragma unroll
  for (int qt = 0; qt < 4; ++qt)
#pragma unroll
    for (int r = 0; r < 4; ++r) {
      int row = 16 * qt + 4 * lg + r;
      uint32_t p = pk2(o[qt][0][r], o[qt][1][r]);
      *reinterpret_cast<uint32_t*>(smem + row * XROWB + h * 64 + 4 * ln) = p;
    }
  __syncthreads();

  // ---- Phase 4: proj GEMM (M=64, N=256, K=256); wave h computes cols h*32..h*32+31 ----
  f32x4 pacc[4][2];
#pragma unroll
  for (int mt = 0; mt < 4; ++mt)
#pragma unroll
    for (int n2 = 0; n2 < 2; ++n2) pacc[mt][n2] = (f32x4){0, 0, 0, 0};
#pragma unroll 2
  for (int ks = 0; ks < 8; ++ks) {
    int k0 = ks * 32 + lg * 8;
    short8 afr[4];
#pragma unroll
    for (int mt = 0; mt < 4; ++mt)
      afr[mt] = *reinterpret_cast<const short8*>(smem + (16 * mt + ln) * XROWB + k0 * 2);
    short8 bfr[2];
#pragma unroll
    for (int n2 = 0; n2 < 2; ++n2)
      bfr[n2] = *reinterpret_cast<const short8*>(projw + (size_t)(h * HD + 16 * n2 + ln) * CDIM + k0);
#pragma unroll
    for (int n2 = 0; n2 < 2; ++n2)
#pragma unroll
      for (int mt = 0; mt < 4; ++mt)
        pacc[mt][n2] = __builtin_amdgcn_mfma_f32_16x16x32_bf16(afr[mt], bfr[n2], pacc[mt][n2], 0, 0, 0);
  }

  // epilogue: bias + scatter (un-roll + crop)
  float pb0 = proj_b[h * HD + ln];
  float pb1 = proj_b[h * HD + 16 + ln];
#pragma unroll
  for (int mt = 0; mt < 4; ++mt)
#pragma unroll
    for (int r = 0; r < 4; ++r) {
      int t = 16 * mt + 4 * lg + r;
      if (t < TOK) {
        int ty = t / WS7, tx = t - WS7 * (t / WS7);
        int sh = wy * WS7 + ty + SHIFT3; if (sh >= HP) sh -= HP;
        int sw = wx * WS7 + tx + SHIFT3; if (sw >= HP) sw -= HP;
        if (sh < HIMG && sw < HIMG) {
          float* po = out + ((size_t)b * (HIMG * HIMG) + sh * HIMG + sw) * CDIM + h * HD + ln;
          po[0]  = pacc[mt][0][r] + pb0;
          po[16] = pacc[mt][1][r] + pb1;
        }
      }
    }
}

extern "C" void kernel_launch(void* const* d_in, const int* in_sizes, int n_in,
                              void* d_out, int out_size, void* d_ws, size_t ws_size,
                              hipStream_t stream) {
  const float* x      = (const float*)d_in[0];
  const float* qkv_w  = (const float*)d_in[1];
  const float* qkv_b  = (const float*)d_in[2];
  const float* proj_w = (const float*)d_in[3];
  const float* proj_b = (const float*)d_in[4];
  float* out          = (float*)d_out;

  short* qkvw_bf = (short*)d_ws;                               // 768*256*2 = 393216 B
  short* projw_bf = (short*)((char*)d_ws + 768 * 256 * 2);     // 256*256*2 = 131072 B

  hipLaunchKernelGGL(cvt_weights, dim3(256), dim3(256), 0, stream,
                     qkv_w, proj_w, qkvw_bf, projw_bf);

  hipFuncSetAttribute((const void*)swin_fused,
                      hipFuncAttributeMaxDynamicSharedMemorySize, SMEM_BYTES);
  hipLaunchKernelGGL(swin_fused, dim3(BATCH * NWIN), dim3(512), SMEM_BYTES, stream,
                     x, qkvw_bf, qkv_b, projw_bf, proj_b, out);
}